// Round 1
// baseline (125.275 us; speedup 1.0000x reference)
//
#include <hip/hip_runtime.h>
#include <hip/hip_bf16.h>

// Match numpy float32 semantics exactly: no FMA contraction, fixed op order.
#pragma clang fp contract(off)

#define B_ 8
#define N_ 4096
#define C_ 128
#define K_ 16      // SAMPLE (output neighbors)
#define S_ 20      // SAMPLE_NUM (ball_query nsample)

// slot s in [0,20) -> output position k = s - 1 - s/5, valid iff s>0 && s%5!=0
// DILATED_IDX = {1,2,3,4, 6,7,8,9, 11,12,13,14, 16,17,18,19}

__global__ __launch_bounds__(256) void bq_kernel(const float* __restrict__ xyz,
                                                 int* __restrict__ idx_out) {
#pragma clang fp contract(off)
    const int wid  = blockIdx.x * (blockDim.x >> 6) + (threadIdx.x >> 6); // query id
    const int lane = threadIdx.x & 63;
    const int b = wid >> 12;      // 4096 queries per batch
    const int n = wid & 4095;
    const float* xb = xyz + (size_t)b * N_ * 3;

    const float qx = xb[n * 3 + 0];
    const float qy = xb[n * 3 + 1];
    const float qz = xb[n * 3 + 2];
    const float sqn = (qx * qx + qy * qy) + qz * qz;

    int cnt = 0;
    int first = -1;
    int* out = idx_out + (size_t)wid * K_;

    for (int base = 0; base < N_; base += 64) {
        const int m = base + lane;
        const float mx = xb[m * 3 + 0];
        const float my = xb[m * 3 + 1];
        const float mz = xb[m * 3 + 2];
        const float sqm = (mx * mx + my * my) + mz * mz;
        const float dot = (qx * mx + qy * my) + qz * mz;
        const float d2  = (sqn + sqm) - 2.0f * dot;
        const bool in = d2 < 256.0f;

        const unsigned long long mask = __ballot(in);
        if (cnt == 0 && mask != 0ull) {
            first = base + __builtin_ctzll(mask);   // uniform across wave
        }
        const unsigned long long below = (lane == 63) ? ~0ull >> 1
                                         : ((1ull << lane) - 1ull);
        // (lane==63 case: (1<<63)-1 is fine too; both give bits below lane)
        const int pre  = __popcll(mask & ((1ull << lane) - 1ull));
        const int slot = cnt + pre;
        if (in && slot < S_ && slot > 0 && (slot % 5) != 0) {
            out[slot - 1 - slot / 5] = m;
        }
        cnt += __popcll(mask);
        if (cnt >= S_) break;
        (void)below;
    }

    // pad slots [cnt, 20) with 'first' (sel==N replaced by sel[...,0])
    if (lane < S_ && lane >= cnt && lane > 0 && (lane % 5) != 0) {
        out[lane - 1 - lane / 5] = first;
    }
}

__global__ __launch_bounds__(256) void gather_kernel(const float* __restrict__ xyz,
                                                     const float* __restrict__ feat,
                                                     const int* __restrict__ idx,
                                                     float* __restrict__ out_xyz,
                                                     float* __restrict__ out_feat) {
    __shared__ float lds[C_ * 17];   // [c][k] padded to 17
    __shared__ int sidx[K_];

    const int bn = blockIdx.x;       // 0..32767
    const int b = bn >> 12;
    const int n = bn & 4095;
    const int t = threadIdx.x;

    if (t < K_) sidx[t] = idx[(size_t)bn * K_ + t];
    __syncthreads();

    // stage 16 feature rows (coalesced 512B rows) into lds[c*17+k]
    const float* fb = feat + (size_t)b * N_ * C_;
    for (int e = t; e < K_ * C_; e += 256) {
        const int k = e >> 7;        // row
        const int c = e & 127;       // col within row
        lds[c * 17 + k] = fb[(size_t)sidx[k] * C_ + c];
    }

    // xyz gather: 3*16 = 48 elements, direct (xyz is L1/L2 resident)
    if (t < 48) {
        const int j = t >> 4;        // 0..2
        const int k = t & 15;
        out_xyz[(((size_t)b * 3 + j) * N_ + n) * K_ + k] =
            xyz[((size_t)b * N_ + sidx[k]) * 3 + j];
    }
    __syncthreads();

    // transposed write: out_feat[((b*C + c)*N + n)*K + k], coalesced 64B runs
    float* ob = out_feat + ((size_t)b * C_ * N_ + (size_t)n) * K_;
    for (int e = t; e < K_ * C_; e += 256) {
        const int c = e >> 4;
        const int k = e & 15;
        ob[(size_t)c * (N_ * K_) + k] = lds[c * 17 + k];
    }
}

extern "C" void kernel_launch(void* const* d_in, const int* in_sizes, int n_in,
                              void* d_out, int out_size, void* d_ws, size_t ws_size,
                              hipStream_t stream) {
    const float* xyz  = (const float*)d_in[0];   // (8, 4096, 3)
    const float* feat = (const float*)d_in[1];   // (8, 4096, 128)

    float* out_xyz  = (float*)d_out;                       // (8,3,4096,16)
    float* out_feat = out_xyz + (size_t)B_ * 3 * N_ * K_;  // (8,128,4096,16)

    int* idx = (int*)d_ws;   // 8*4096*16 int32 = 2 MB scratch

    // 32768 queries, one wave each, 4 waves per 256-thread block
    hipLaunchKernelGGL(bq_kernel, dim3((B_ * N_) / 4), dim3(256), 0, stream,
                       xyz, idx);
    // one block per (b, n)
    hipLaunchKernelGGL(gather_kernel, dim3(B_ * N_), dim3(256), 0, stream,
                       xyz, feat, idx, out_xyz, out_feat);
}

// Round 3
// 113.730 us; speedup vs baseline: 1.1015x; 1.1015x over previous
//
#include <hip/hip_runtime.h>
#include <hip/hip_bf16.h>

// Match numpy float32 semantics exactly: no FMA contraction, fixed op order.
#pragma clang fp contract(off)

#define B_ 8
#define N_ 4096
#define C_ 128
#define K_ 16      // SAMPLE (output neighbors)
#define S_ 20      // SAMPLE_NUM (ball_query nsample)
#define NT 2       // queries per block -> full 128-B line writes on drain

// slot s in [0,20) -> output position k = s - 1 - s/5, valid iff s>0 && s%5!=0
// DILATED_IDX = {1,2,3,4, 6,7,8,9, 11,12,13,14, 16,17,18,19}

// Fused: phase A = per-wave ball query (waves 0..NT-1, one query each) ->
// indices kept in LDS (no global intermediate, no cross-kernel hazard).
// Phase B = LDS-staged transpose gather with full-line coalesced writes.
__global__ __launch_bounds__(256) void fused_kernel(const float* __restrict__ xyz,
                                                    const float* __restrict__ feat,
                                                    float* __restrict__ out_xyz,
                                                    float* __restrict__ out_feat) {
#pragma clang fp contract(off)
    __shared__ float lds[NT][C_ * 17];   // [nl][c*17+k], padded: conflict-free both sides
    __shared__ int sidx[NT * K_];

    // XCD-aware remap: blocks round-robin across 8 XCDs by hw id, so put all
    // blocks of batch b on XCD b -> per-XCD L2 working set = 2 MB (resident).
    const int w    = blockIdx.x;          // 0..16383
    const int b    = w & 7;
    const int n0   = (w >> 3) * NT;       // 0,2,..,4094
    const int t    = threadIdx.x;
    const int wave = t >> 6;
    const int lane = t & 63;
    const float* xb = xyz + (size_t)b * N_ * 3;

    // ---------------- Phase A: ball query, one wave per query ----------------
    if (wave < NT) {
        const int n = n0 + wave;
        const float qx = xb[n * 3 + 0];
        const float qy = xb[n * 3 + 1];
        const float qz = xb[n * 3 + 2];
        const float sqn = (qx * qx + qy * qy) + qz * qz;

        int cnt = 0;
        int first = -1;
        int* out = sidx + wave * K_;

        for (int base = 0; base < N_; base += 64) {
            const int m = base + lane;
            const float mx = xb[m * 3 + 0];
            const float my = xb[m * 3 + 1];
            const float mz = xb[m * 3 + 2];
            const float sqm = (mx * mx + my * my) + mz * mz;
            const float dot = (qx * mx + qy * my) + qz * mz;
            const float d2  = (sqn + sqm) - 2.0f * dot;
            const bool in = d2 < 256.0f;

            const unsigned long long mask = __ballot(in);
            if (cnt == 0 && mask != 0ull) {
                first = base + __builtin_ctzll(mask);   // wave-uniform
            }
            const int pre  = __popcll(mask & ((1ull << lane) - 1ull));
            const int slot = cnt + pre;
            if (in && slot < S_ && slot > 0 && (slot % 5) != 0) {
                out[slot - 1 - slot / 5] = m;
            }
            cnt += __popcll(mask);       // wave-uniform
            if (cnt >= S_) break;        // wave-uniform exit
        }

        // pad slots [cnt, 20) with 'first' (sel==N replaced by sel[...,0])
        if (lane < S_ && lane >= cnt && lane > 0 && (lane % 5) != 0) {
            out[lane - 1 - lane / 5] = first;
        }
    }
    __syncthreads();   // sidx visible to all waves

    // ---------------- Phase B: gather ----------------
    // stage NT*16 feature rows (coalesced 512-B rows) into lds
    const float* fb = feat + (size_t)b * N_ * C_;
    for (int e = t; e < NT * K_ * C_; e += 256) {
        const int nl = e >> 11;          // 0..NT-1
        const int k  = (e >> 7) & 15;
        const int c  = e & 127;
        lds[nl][c * 17 + k] = fb[(size_t)sidx[nl * K_ + k] * C_ + c];
    }

    // xyz gather: NT*3*16 = 96 elements (xyz is cache resident)
    if (t < NT * 48) {
        const int nl = t / 48;
        const int r  = t % 48;
        const int j  = r >> 4;           // 0..2
        const int k  = r & 15;
        out_xyz[(((size_t)b * 3 + j) * N_ + (n0 + nl)) * K_ + k] =
            xb[(size_t)sidx[nl * K_ + k] * 3 + j];
    }
    __syncthreads();

    // drain: per c, NT*16 = 32 dwords = one full aligned 128-B line.
    // wave64 covers 2 c's -> 2 full-line transactions per store instruction.
    float* ob = out_feat + (size_t)b * C_ * N_ * K_ + (size_t)n0 * K_;
    for (int e = t; e < NT * K_ * C_; e += 256) {
        const int c  = e >> 5;           // 0..127
        const int r  = e & 31;
        const int nl = r >> 4;
        const int k  = r & 15;
        ob[(size_t)c * (N_ * K_) + nl * K_ + k] = lds[nl][c * 17 + k];
    }
}

extern "C" void kernel_launch(void* const* d_in, const int* in_sizes, int n_in,
                              void* d_out, int out_size, void* d_ws, size_t ws_size,
                              hipStream_t stream) {
    const float* xyz  = (const float*)d_in[0];   // (8, 4096, 3)
    const float* feat = (const float*)d_in[1];   // (8, 4096, 128)

    float* out_xyz  = (float*)d_out;                       // (8,3,4096,16)
    float* out_feat = out_xyz + (size_t)B_ * 3 * N_ * K_;  // (8,128,4096,16)

    // one block per (b, n-pair); fully fused, no workspace use
    hipLaunchKernelGGL(fused_kernel, dim3(B_ * N_ / NT), dim3(256), 0, stream,
                       xyz, feat, out_xyz, out_feat);
}